// Round 8
// baseline (256.458 us; speedup 1.0000x reference)
//
#include <hip/hip_runtime.h>
#include <cstdint>

typedef unsigned short u16;
typedef __attribute__((ext_vector_type(8))) short short8;
typedef __attribute__((ext_vector_type(4))) short short4v;
typedef __attribute__((ext_vector_type(4))) float f32x4;

#define NTOK 2048
#define CDIM 1024
#define C3   3072
#define NH   8
#define HD   128

__device__ __forceinline__ float bf2f(u16 u) {
    return __uint_as_float(((unsigned)u) << 16);
}
__device__ __forceinline__ u16 f2bf(float f) {
    unsigned u = __float_as_uint(f);
    u += 0x7fffu + ((u >> 16) & 1u);
    return (u16)(u >> 16);
}
// async 16B global->LDS DMA; LDS dest must be wave-uniform base + lane*16
__device__ __forceinline__ void gld_lds16(const u16* g, u16* l) {
    __builtin_amdgcn_global_load_lds(
        (__attribute__((address_space(1))) void*)(u16*)g,
        (__attribute__((address_space(3))) void*)l, 16, 0, 0);
}

// ---------------------------------------------------------------- K0: f32->bf16
__global__ __launch_bounds__(256) void k_cast(const float* __restrict__ x,
                                              const float* __restrict__ w,
                                              u16* __restrict__ xb,
                                              u16* __restrict__ wb) {
    int t = blockIdx.x * blockDim.x + threadIdx.x;
    int stride = gridDim.x * blockDim.x;
    for (int i = t; i < (NTOK * CDIM) / 4; i += stride) {
        float4 v = ((const float4*)x)[i];
        ushort4 o;
        o.x = f2bf(v.x); o.y = f2bf(v.y); o.z = f2bf(v.z); o.w = f2bf(v.w);
        ((ushort4*)xb)[i] = o;
    }
    for (int i = t; i < (C3 * CDIM) / 4; i += stride) {
        float4 v = ((const float4*)w)[i];
        ushort4 o;
        o.x = f2bf(v.x); o.y = f2bf(v.y); o.z = f2bf(v.z); o.w = f2bf(v.w);
        ((ushort4*)wb)[i] = o;
    }
}

// ---------------------------------------------------------------- K1: m97-style bf16 GEMM, C = A[M,K] @ B[N,K]^T
// EPI 0: write bf16. EPI 1: write u8 (acc*scale > 0.75).
template <int EPI>
__global__ __launch_bounds__(256) void k_gemm16(const u16* __restrict__ A,
                                                const u16* __restrict__ B,
                                                void* __restrict__ Cv, int K,
                                                int lda, int ldb, int ldc,
                                                float scale) {
    __shared__ u16 As[128 * 32];
    __shared__ u16 Bs[128 * 32];
    const int tid = threadIdx.x;
    const int lane = tid & 63;
    const int wid = tid >> 6;
    const int wm = wid >> 1, wn = wid & 1;
    const int q = lane >> 4, l16 = lane & 15;
    const int m0 = blockIdx.y * 128, n0 = blockIdx.x * 128;

    f32x4 zero4 = {0.f, 0.f, 0.f, 0.f};
    f32x4 acc[4][4];
#pragma unroll
    for (int i = 0; i < 4; i++)
#pragma unroll
        for (int j = 0; j < 4; j++) acc[i][j] = zero4;

    const int s0 = tid, r0 = s0 >> 2, c0 = (s0 & 3) * 8;
    const int s1 = tid + 256, r1 = s1 >> 2, c1 = (s1 & 3) * 8;
    const u16* a0 = &A[(long long)(m0 + r0) * lda + c0];
    const u16* b0 = &B[(long long)(n0 + r0) * ldb + c0];
    const u16* a1 = &A[(long long)(m0 + r1) * lda + c1];
    const u16* b1 = &B[(long long)(n0 + r1) * ldb + c1];

    for (int k0 = 0; k0 < K; k0 += 32) {
        __syncthreads();
        gld_lds16(a0 + k0, &As[s0 * 8]);
        gld_lds16(b0 + k0, &Bs[s0 * 8]);
        gld_lds16(a1 + k0, &As[s1 * 8]);
        gld_lds16(b1 + k0, &Bs[s1 * 8]);
        __syncthreads();
        short8 af[4], bfr[4];
#pragma unroll
        for (int tm = 0; tm < 4; tm++)
            af[tm] = *(const short8*)&As[(wm * 64 + tm * 16 + l16) * 32 + q * 8];
#pragma unroll
        for (int tn = 0; tn < 4; tn++)
            bfr[tn] = *(const short8*)&Bs[(wn * 64 + tn * 16 + l16) * 32 + q * 8];
#pragma unroll
        for (int tm = 0; tm < 4; tm++)
#pragma unroll
            for (int tn = 0; tn < 4; tn++)
                acc[tm][tn] = __builtin_amdgcn_mfma_f32_16x16x32_bf16(
                    af[tm], bfr[tn], acc[tm][tn], 0, 0, 0);
    }

#pragma unroll
    for (int tm = 0; tm < 4; tm++)
#pragma unroll
        for (int tn = 0; tn < 4; tn++)
#pragma unroll
            for (int r = 0; r < 4; r++) {
                int row = m0 + wm * 64 + tm * 16 + q * 4 + r;
                int col = n0 + wn * 64 + tn * 16 + l16;
                float v = acc[tm][tn][r];
                long long off = (long long)row * ldc + col;
                if (EPI == 0) {
                    ((u16*)Cv)[off] = f2bf(v);
                } else {
                    ((unsigned char*)Cv)[off] = (v * scale > 0.75f) ? 1 : 0;
                }
            }
}

// ---------------------------------------------------------------- K2: per-row L2 normalize q/k/v heads + x_ori (x8 vec)
__global__ __launch_bounds__(256) void k_norm(const u16* __restrict__ qkv,
                                              u16* __restrict__ Qn,
                                              u16* __restrict__ Kn,
                                              u16* __restrict__ Vn,
                                              float* __restrict__ out) {
    const int n = blockIdx.x;
    const int t = threadIdx.x;
    const int g16 = t >> 4;      // 0..15: 16-lane group
    const int l16 = t & 15;
    const int d0 = l16 * 8;
#pragma unroll
    for (int s = 0; s < 2; s++) {
        int row = s * 16 + g16;  // 0..31, need 0..23
        if (row < 24) {
            int which = row >> 3;  // 0=q 1=k 2=v
            int h = row & 7;
            const u16* src = qkv + (long long)n * C3 + which * CDIM + h * HD + d0;
            short8 v8 = *(const short8*)src;
            float f[8];
            float ss = 0.f;
#pragma unroll
            for (int k = 0; k < 8; k++) {
                f[k] = bf2f((u16)v8[k]);
                ss += f[k] * f[k];
            }
            ss += __shfl_xor(ss, 1);
            ss += __shfl_xor(ss, 2);
            ss += __shfl_xor(ss, 4);
            ss += __shfl_xor(ss, 8);
            float rn = rsqrtf(ss);
            u16* dst = (which == 0 ? Qn : which == 1 ? Kn : Vn) +
                       (long long)n * CDIM + h * HD + d0;
            short8 o8;
#pragma unroll
            for (int k = 0; k < 8; k++) o8[k] = (short)f2bf(f[k] * rn);
            *(short8*)dst = o8;
            if (which == 2) {
                float4 a, b;
                a.x = f[0]; a.y = f[1]; a.z = f[2]; a.w = f[3];
                b.x = f[4]; b.y = f[5]; b.z = f[6]; b.w = f[7];
                float* od = &out[(long long)n * 2048 + 1024 + h * HD + d0];
                *(float4*)od = a;
                *(float4*)(od + 4) = b;
            }
        }
    }
}

// ---------------------------------------------------------------- K2b: tiled transpose Vt[c][n] = v[n][c] (raw v)
__global__ __launch_bounds__(256) void k_vt(const u16* __restrict__ qkv,
                                            u16* __restrict__ Vt) {
    __shared__ u16 T[64][72];
    const int n0 = blockIdx.x * 64;
    const int c0 = blockIdx.y * 64;
    const int tid = threadIdx.x;
    {
        int nl = tid >> 2, cc = (tid & 3) * 16;
        const u16* src = &qkv[(long long)(n0 + nl) * C3 + 2 * CDIM + c0 + cc];
        *(short8*)&T[nl][cc] = *(const short8*)&src[0];
        *(short8*)&T[nl][cc + 8] = *(const short8*)&src[8];
    }
    __syncthreads();
    {
        int cl = tid >> 2, nc = (tid & 3) * 16;
        ushort va[16];
#pragma unroll
        for (int i = 0; i < 16; i++) va[i] = T[nc + i][cl];
        u16* dst = &Vt[(long long)(c0 + cl) * NTOK + n0 + nc];
        *(short8*)&dst[0] = *(short8*)&va[0];
        *(short8*)&dst[8] = *(short8*)&va[8];
    }
}

// ---------------------------------------------------------------- K3: fused QK->exp->P + PV, DMA staging, 4 blocks/CU
// grid (32 i-tiles, 4 j-chunks, 8 heads) = 1024 blocks; LDS 40960 B
__global__ __launch_bounds__(256, 4) void k_attn8(const u16* __restrict__ Qn,
                                                  const u16* __restrict__ Kn,
                                                  const u16* __restrict__ Vt,
                                                  const float* __restrict__ cls,
                                                  u16* __restrict__ P,
                                                  float* __restrict__ Spart,
                                                  u16* __restrict__ Xpart) {
    __shared__ u16 Kf[8192];  // QK B-frags, 16 groups: slot ((tn*4+kt)*64+lane)*8
    __shared__ u16 Vf[8192];  // PV B-frags, 16 groups: slot ((n*2+ks)*64+lane)*8
    __shared__ u16 Et[4096];  // e tile 64x64 bf16, XOR-chunk swizzled
    const int h = blockIdx.z;
    const int jc = blockIdx.y;
    const int i0 = blockIdx.x * 64;
    const int jbase = jc * 512;
    const int tid = threadIdx.x, lane = tid & 63, wid = tid >> 6;
    const int q = lane >> 4, l16 = lane & 15;
    const int wm = wid >> 1, wn = wid & 1;

    // resident Q fragments (i range: wm*32 .. +31)
    short8 af[2][4];
#pragma unroll
    for (int m = 0; m < 2; m++)
#pragma unroll
        for (int kt = 0; kt < 4; kt++)
            af[m][kt] = *(const short8*)&Qn[(long long)(i0 + wm * 32 + m * 16 + l16) * CDIM +
                                            h * HD + kt * 32 + q * 8];
    float cls_i[2][4];
#pragma unroll
    for (int m = 0; m < 2; m++)
#pragma unroll
        for (int r = 0; r < 4; r++)
            cls_i[m][r] = cls[i0 + wm * 32 + m * 16 + q * 4 + r] - 0.1f;

    // DMA gather sources: wave `wid` owns groups wid*4..wid*4+3 for Kf and Vf.
    const u16* ksrc[4];
    const u16* vsrc[4];
#pragma unroll
    for (int t = 0; t < 4; t++) {
        int g = wid * 4 + t;
        int tn = g >> 2, kt = g & 3;
        ksrc[t] = &Kn[(long long)(jbase + tn * 16 + l16) * CDIM + h * HD + kt * 32 + q * 8];
        int n = g >> 1, ks = g & 1;
        vsrc[t] = &Vt[(long long)(h * HD + n * 16 + l16) * NTOK + jbase + (ks * 4 + q) * 8];
    }

    f32x4 zero4 = {0.f, 0.f, 0.f, 0.f};
    f32x4 pv[2][4];
#pragma unroll
    for (int m = 0; m < 2; m++)
#pragma unroll
        for (int n = 0; n < 4; n++) pv[m][n] = zero4;
    float sums[2][4] = {{0.f, 0.f, 0.f, 0.f}, {0.f, 0.f, 0.f, 0.f}};

    for (int jt = 0; jt < 8; ++jt) {
        const int j0 = jbase + jt * 64;
        __syncthreads();  // previous-iter consumers done with Kf/Vf/Et
#pragma unroll
        for (int t = 0; t < 4; t++) {
            int g = wid * 4 + t;
            gld_lds16(ksrc[t], &Kf[(g * 64 + lane) * 8]);
            gld_lds16(vsrc[t], &Vf[(g * 64 + lane) * 8]);
            ksrc[t] += 64 * CDIM;
            vsrc[t] += 64;
        }
        __syncthreads();  // drains DMA (vmcnt) + LDS visible
        // QK -> e -> Et (+ row sums)
#pragma unroll
        for (int tn = 0; tn < 2; tn++) {
            int tng = wn * 2 + tn;
            short8 bfr[4];
#pragma unroll
            for (int kt = 0; kt < 4; kt++)
                bfr[kt] = *(const short8*)&Kf[((tng * 4 + kt) * 64 + lane) * 8];
            int j = j0 + tng * 16 + l16;
            float cj = cls[j];
            float sc = 25.f * cj;
#pragma unroll
            for (int m = 0; m < 2; m++) {
                f32x4 acc = zero4;
#pragma unroll
                for (int kt = 0; kt < 4; kt++)
                    acc = __builtin_amdgcn_mfma_f32_16x16x32_bf16(af[m][kt], bfr[kt],
                                                                  acc, 0, 0, 0);
                int ibase = wm * 32 + m * 16 + q * 4;
#pragma unroll
                for (int r = 0; r < 4; r++) {
                    float mk = (cj > cls_i[m][r]) ? 1.f : 0.f;
                    float e = __expf(acc[r] * sc * mk);
                    sums[m][r] += e;
                    int il = ibase + r;
                    int jl = tng * 16 + l16;
                    Et[il * 64 + ((((jl >> 3) ^ (il & 7)) << 3) | (jl & 7))] = f2bf(e);
                }
            }
        }
        __syncthreads();
        {   // coalesced P store from Et
            int il = tid >> 2, c = tid & 3;
            int x = il & 7;
            short8 e0 = *(const short8*)&Et[il * 64 + (((2 * c) ^ x) << 3)];
            short8 e1 = *(const short8*)&Et[il * 64 + (((2 * c + 1) ^ x) << 3)];
            u16* dst = &P[((long long)(h * NTOK + i0 + il)) * NTOK + j0 + c * 16];
            *(short8*)&dst[0] = e0;
            *(short8*)&dst[8] = e1;
        }
        // PV: A from Et (swizzled), B from Vf; out tile i(64) x d(128)
#pragma unroll
        for (int ks = 0; ks < 2; ks++) {
            short8 a2[2];
#pragma unroll
            for (int m2 = 0; m2 < 2; m2++) {
                int il = wm * 32 + m2 * 16 + l16;
                int ch = ks * 4 + q;
                a2[m2] = *(const short8*)&Et[il * 64 + ((ch ^ (il & 7)) << 3)];
            }
#pragma unroll
            for (int n2 = 0; n2 < 4; n2++) {
                short8 b2 = *(const short8*)&Vf[(((wn * 4 + n2) * 2 + ks) * 64 + lane) * 8];
#pragma unroll
                for (int m2 = 0; m2 < 2; m2++)
                    pv[m2][n2] = __builtin_amdgcn_mfma_f32_16x16x32_bf16(
                        a2[m2], b2, pv[m2][n2], 0, 0, 0);
            }
        }
    }
    // row-sum partials (race-free: one writer per (wn,jc,h,row))
#pragma unroll
    for (int m = 0; m < 2; m++)
#pragma unroll
        for (int r = 0; r < 4; r++) {
            float s = sums[m][r];
            s += __shfl_xor(s, 1);
            s += __shfl_xor(s, 2);
            s += __shfl_xor(s, 4);
            s += __shfl_xor(s, 8);
            if (l16 == 0)
                Spart[((wn * 4 + jc) * NH + h) * NTOK + i0 + wm * 32 + m * 16 + q * 4 + r] = s;
        }
    // store PV partial to this jc's slab (bf16, plain stores, no atomics)
    u16* Xp = Xpart + (long long)jc * NTOK * CDIM;
#pragma unroll
    for (int m2 = 0; m2 < 2; m2++)
#pragma unroll
        for (int n2 = 0; n2 < 4; n2++)
#pragma unroll
            for (int r = 0; r < 4; r++) {
                int i = i0 + wm * 32 + m2 * 16 + q * 4 + r;
                int d = wn * 64 + n2 * 16 + l16;
                Xp[(long long)i * CDIM + h * HD + d] = f2bf(pv[m2][n2][r]);
            }
}

// ---------------------------------------------------------------- K4: merged epilogue: x=(sum Xpart)/S  and  output2
__global__ __launch_bounds__(256) void k_epi(const u16* __restrict__ Xpart,
                                             const float* __restrict__ Spart,
                                             const u16* __restrict__ P,
                                             const unsigned char* __restrict__ mask,
                                             float* __restrict__ out,
                                             float* __restrict__ out2) {
    __shared__ float red[256];
    __shared__ float sArr[NH];
    const int i = blockIdx.x;
    const int t = threadIdx.x;
    if (t < NH) {
        float s = 0.f;
#pragma unroll
        for (int g = 0; g < 8; g++) s += Spart[(g * NH + t) * NTOK + i];
        sArr[t] = s;
    }
    __syncthreads();
    // ---- part A: x row i (1024 cols, 4 per thread)
    {
        int c = t * 4;
        int h = c >> 7;
        float acc[4] = {0.f, 0.f, 0.f, 0.f};
#pragma unroll
        for (int jc = 0; jc < 4; jc++) {
            short4v v = *(const short4v*)&Xpart[(long long)jc * NTOK * CDIM +
                                                (long long)i * CDIM + c];
#pragma unroll
            for (int k = 0; k < 4; k++) acc[k] += bf2f((u16)v[k]);
        }
        float invs = 1.f / sArr[h];
        float4 o;
        o.x = acc[0] * invs; o.y = acc[1] * invs; o.z = acc[2] * invs; o.w = acc[3] * invs;
        *(float4*)&out[(long long)i * 2048 + c] = o;
    }
    // ---- part B: output2 row i (2048 cols, 8 per thread)
    float invS[NH];
#pragma unroll
    for (int h = 0; h < NH; h++) invS[h] = 1.f / (8.f * sArr[h]);
    const int c0 = t * 8;
    float a[8] = {0.f, 0.f, 0.f, 0.f, 0.f, 0.f, 0.f, 0.f};
#pragma unroll
    for (int h = 0; h < NH; h++) {
        short8 p = *(const short8*)&P[((long long)h * NTOK + i) * NTOK + c0];
#pragma unroll
        for (int k = 0; k < 8; k++) a[k] += bf2f((u16)p[k]) * invS[h];
    }
    const unsigned char* mrow = mask + (long long)i * NTOK + c0;
    float e[8];
    unsigned char mk[8];
    float part = 0.f;
#pragma unroll
    for (int k = 0; k < 8; k++) {
        e[k] = __expf(a[k]);
        mk[k] = mrow[k];
        if (mk[k]) part += e[k];
    }
    red[t] = part;
    __syncthreads();
    for (int s = 128; s > 0; s >>= 1) {
        if (t < s) red[t] += red[t + s];
        __syncthreads();
    }
    float invT = 1.f / red[0];
    float o[8];
#pragma unroll
    for (int k = 0; k < 8; k++) o[k] = mk[k] ? e[k] * invT : 0.f;
    float4 o0, o1;
    o0.x = o[0]; o0.y = o[1]; o0.z = o[2]; o0.w = o[3];
    o1.x = o[4]; o1.y = o[5]; o1.z = o[6]; o1.w = o[7];
    float* dst = out2 + (long long)i * NTOK + c0;
    *(float4*)dst = o0;
    *(float4*)(dst + 4) = o1;
}

// ---------------------------------------------------------------- launcher
extern "C" void kernel_launch(void* const* d_in, const int* in_sizes, int n_in,
                              void* d_out, int out_size, void* d_ws,
                              size_t ws_size, hipStream_t stream) {
    (void)in_sizes; (void)n_in; (void)out_size; (void)ws_size;
    const float* x = (const float*)d_in[0];
    const float* cls = (const float*)d_in[1];
    // d_in[2] = fg_score: unused by the reference
    const float* Wq = (const float*)d_in[3];
    float* out = (float*)d_out;
    char* ws = (char*)d_ws;

    // Region [0, 23068672): early buffers (Xb/Wb dead after QKV gemm; QKVb dead
    // after k_vt) overlaid with Xpart/Spart (written only by k_attn8 afterwards).
    u16* Xb = (u16*)(ws + 0);                      //  4 MB  [2048,1024]
    u16* Wb = (u16*)(ws + 4194304);                //  6 MB  [3072,1024]
    u16* QKVb = (u16*)(ws + 10485760);             // 12.6MB [2048,3072]
    u16* Xpart = (u16*)(ws + 0);                   // 16 MB  [4][2048,1024] bf16 PV partials
    float* Spart = (float*)(ws + 16777216);        // 512 KB [8][8,2048] row-sum partials
    u16* Qn = (u16*)(ws + 23068672);               //  4 MB
    u16* Kn = (u16*)(ws + 27262976);               //  4 MB
    u16* Vn = (u16*)(ws + 31457280);               //  4 MB
    u16* Vt = (u16*)(ws + 35651584);               //  4 MB  [1024,2048]
    unsigned char* mask = (unsigned char*)(ws + 39845888);  // 4 MB [2048,2048]
    u16* P = (u16*)(ws + 44040192);                // 67 MB [8,2048,2048]

    // 1. cast x and W to bf16
    k_cast<<<1024, 256, 0, stream>>>(x, Wq, Xb, Wb);

    // 2. QKV = Xb @ Wb^T -> bf16 [2048,3072]  (DMA GEMM)
    k_gemm16<0><<<dim3(C3 / 128, NTOK / 128), 256, 0, stream>>>(
        Xb, Wb, QKVb, CDIM, CDIM, CDIM, C3, 1.f);

    // 3. normalize q/k/v, write x_ori
    k_norm<<<NTOK, 256, 0, stream>>>(QKVb, Qn, Kn, Vn, out);

    // 3b. Vt = v^T (raw v), tiled transpose
    k_vt<<<dim3(NTOK / 64, CDIM / 64), 256, 0, stream>>>(QKVb, Vt);

    // 4. sim mask = (Vn @ Vn^T / 8 > 0.75) -> u8  (DMA GEMM)
    k_gemm16<1><<<dim3(16, 16), 256, 0, stream>>>(
        Vn, Vn, mask, CDIM, CDIM, CDIM, NTOK, 0.125f);

    // 5. fused logits+exp -> P, partial row sums, partial PV -> Xpart
    k_attn8<<<dim3(32, 4, NH), 256, 0, stream>>>(Qn, Kn, Vt, cls, P, Spart, Xpart);

    // 6. merged epilogue: x and output2
    k_epi<<<NTOK, 256, 0, stream>>>(Xpart, Spart, P, mask, out,
                                    out + (long long)NTOK * 2048);
}

// Round 9
// 232.125 us; speedup vs baseline: 1.1048x; 1.1048x over previous
//
#include <hip/hip_runtime.h>
#include <cstdint>

typedef unsigned short u16;
typedef __attribute__((ext_vector_type(8))) short short8;
typedef __attribute__((ext_vector_type(4))) short short4v;
typedef __attribute__((ext_vector_type(4))) float f32x4;

#define NTOK 2048
#define CDIM 1024
#define C3   3072
#define NH   8
#define HD   128

__device__ __forceinline__ float bf2f(u16 u) {
    return __uint_as_float(((unsigned)u) << 16);
}
__device__ __forceinline__ u16 f2bf(float f) {
    unsigned u = __float_as_uint(f);
    u += 0x7fffu + ((u >> 16) & 1u);
    return (u16)(u >> 16);
}
// async 16B global->LDS DMA; LDS dest must be wave-uniform base + lane*16
__device__ __forceinline__ void gld_lds16(const u16* g, u16* l) {
    __builtin_amdgcn_global_load_lds(
        (__attribute__((address_space(1))) void*)(u16*)g,
        (__attribute__((address_space(3))) void*)l, 16, 0, 0);
}

// ---------------------------------------------------------------- K0: f32->bf16
__global__ __launch_bounds__(256) void k_cast(const float* __restrict__ x,
                                              const float* __restrict__ w,
                                              u16* __restrict__ xb,
                                              u16* __restrict__ wb) {
    int t = blockIdx.x * blockDim.x + threadIdx.x;
    int stride = gridDim.x * blockDim.x;
    for (int i = t; i < (NTOK * CDIM) / 4; i += stride) {
        float4 v = ((const float4*)x)[i];
        ushort4 o;
        o.x = f2bf(v.x); o.y = f2bf(v.y); o.z = f2bf(v.z); o.w = f2bf(v.w);
        ((ushort4*)xb)[i] = o;
    }
    for (int i = t; i < (C3 * CDIM) / 4; i += stride) {
        float4 v = ((const float4*)w)[i];
        ushort4 o;
        o.x = f2bf(v.x); o.y = f2bf(v.y); o.z = f2bf(v.z); o.w = f2bf(v.w);
        ((ushort4*)wb)[i] = o;
    }
}

// ---------------------------------------------------------------- K1: m97-style bf16 GEMM, C = A[M,K] @ B[N,K]^T
// EPI 0: write bf16. EPI 2: symmetric u8 mask (only bx<=by blocks run; writes
// both (row,col) and (col,row)).
template <int EPI>
__global__ __launch_bounds__(256) void k_gemm16(const u16* __restrict__ A,
                                                const u16* __restrict__ B,
                                                void* __restrict__ Cv, int K,
                                                int lda, int ldb, int ldc,
                                                float scale) {
    if (EPI == 2 && blockIdx.x > blockIdx.y) return;  // symmetric: skip upper
    __shared__ u16 As[128 * 32];
    __shared__ u16 Bs[128 * 32];
    const int tid = threadIdx.x;
    const int lane = tid & 63;
    const int wid = tid >> 6;
    const int wm = wid >> 1, wn = wid & 1;
    const int q = lane >> 4, l16 = lane & 15;
    const int m0 = blockIdx.y * 128, n0 = blockIdx.x * 128;

    f32x4 zero4 = {0.f, 0.f, 0.f, 0.f};
    f32x4 acc[4][4];
#pragma unroll
    for (int i = 0; i < 4; i++)
#pragma unroll
        for (int j = 0; j < 4; j++) acc[i][j] = zero4;

    const int s0 = tid, r0 = s0 >> 2, c0 = (s0 & 3) * 8;
    const int s1 = tid + 256, r1 = s1 >> 2, c1 = (s1 & 3) * 8;
    const u16* a0 = &A[(long long)(m0 + r0) * lda + c0];
    const u16* b0 = &B[(long long)(n0 + r0) * ldb + c0];
    const u16* a1 = &A[(long long)(m0 + r1) * lda + c1];
    const u16* b1 = &B[(long long)(n0 + r1) * ldb + c1];

    for (int k0 = 0; k0 < K; k0 += 32) {
        __syncthreads();
        gld_lds16(a0 + k0, &As[s0 * 8]);
        gld_lds16(b0 + k0, &Bs[s0 * 8]);
        gld_lds16(a1 + k0, &As[s1 * 8]);
        gld_lds16(b1 + k0, &Bs[s1 * 8]);
        __syncthreads();
        short8 af[4], bfr[4];
#pragma unroll
        for (int tm = 0; tm < 4; tm++)
            af[tm] = *(const short8*)&As[(wm * 64 + tm * 16 + l16) * 32 + q * 8];
#pragma unroll
        for (int tn = 0; tn < 4; tn++)
            bfr[tn] = *(const short8*)&Bs[(wn * 64 + tn * 16 + l16) * 32 + q * 8];
#pragma unroll
        for (int tm = 0; tm < 4; tm++)
#pragma unroll
            for (int tn = 0; tn < 4; tn++)
                acc[tm][tn] = __builtin_amdgcn_mfma_f32_16x16x32_bf16(
                    af[tm], bfr[tn], acc[tm][tn], 0, 0, 0);
    }

#pragma unroll
    for (int tm = 0; tm < 4; tm++)
#pragma unroll
        for (int tn = 0; tn < 4; tn++)
#pragma unroll
            for (int r = 0; r < 4; r++) {
                int row = m0 + wm * 64 + tm * 16 + q * 4 + r;
                int col = n0 + wn * 64 + tn * 16 + l16;
                float v = acc[tm][tn][r];
                if (EPI == 0) {
                    ((u16*)Cv)[(long long)row * ldc + col] = f2bf(v);
                } else {
                    unsigned char b = (v * scale > 0.75f) ? 1 : 0;
                    ((unsigned char*)Cv)[(long long)row * ldc + col] = b;
                    ((unsigned char*)Cv)[(long long)col * ldc + row] = b;
                }
            }
}

// ---------------------------------------------------------------- K2: per-row L2 normalize q/k/v heads + x_ori (x8 vec)
__global__ __launch_bounds__(256) void k_norm(const u16* __restrict__ qkv,
                                              u16* __restrict__ Qn,
                                              u16* __restrict__ Kn,
                                              u16* __restrict__ Vn,
                                              float* __restrict__ out) {
    const int n = blockIdx.x;
    const int t = threadIdx.x;
    const int g16 = t >> 4;      // 0..15: 16-lane group
    const int l16 = t & 15;
    const int d0 = l16 * 8;
#pragma unroll
    for (int s = 0; s < 2; s++) {
        int row = s * 16 + g16;  // 0..31, need 0..23
        if (row < 24) {
            int which = row >> 3;  // 0=q 1=k 2=v
            int h = row & 7;
            const u16* src = qkv + (long long)n * C3 + which * CDIM + h * HD + d0;
            short8 v8 = *(const short8*)src;
            float f[8];
            float ss = 0.f;
#pragma unroll
            for (int k = 0; k < 8; k++) {
                f[k] = bf2f((u16)v8[k]);
                ss += f[k] * f[k];
            }
            ss += __shfl_xor(ss, 1);
            ss += __shfl_xor(ss, 2);
            ss += __shfl_xor(ss, 4);
            ss += __shfl_xor(ss, 8);
            float rn = rsqrtf(ss);
            u16* dst = (which == 0 ? Qn : which == 1 ? Kn : Vn) +
                       (long long)n * CDIM + h * HD + d0;
            short8 o8;
#pragma unroll
            for (int k = 0; k < 8; k++) o8[k] = (short)f2bf(f[k] * rn);
            *(short8*)dst = o8;
            if (which == 2) {
                float4 a, b;
                a.x = f[0]; a.y = f[1]; a.z = f[2]; a.w = f[3];
                b.x = f[4]; b.y = f[5]; b.z = f[6]; b.w = f[7];
                float* od = &out[(long long)n * 2048 + 1024 + h * HD + d0];
                *(float4*)od = a;
                *(float4*)(od + 4) = b;
            }
        }
    }
}

// ---------------------------------------------------------------- K2b: tiled transpose Vt[c][n] = v[n][c] (raw v)
__global__ __launch_bounds__(256) void k_vt(const u16* __restrict__ qkv,
                                            u16* __restrict__ Vt) {
    __shared__ u16 T[64][72];
    const int n0 = blockIdx.x * 64;
    const int c0 = blockIdx.y * 64;
    const int tid = threadIdx.x;
    {
        int nl = tid >> 2, cc = (tid & 3) * 16;
        const u16* src = &qkv[(long long)(n0 + nl) * C3 + 2 * CDIM + c0 + cc];
        *(short8*)&T[nl][cc] = *(const short8*)&src[0];
        *(short8*)&T[nl][cc + 8] = *(const short8*)&src[8];
    }
    __syncthreads();
    {
        int cl = tid >> 2, nc = (tid & 3) * 16;
        ushort va[16];
#pragma unroll
        for (int i = 0; i < 16; i++) va[i] = T[nc + i][cl];
        u16* dst = &Vt[(long long)(c0 + cl) * NTOK + n0 + nc];
        *(short8*)&dst[0] = *(short8*)&va[0];
        *(short8*)&dst[8] = *(short8*)&va[8];
    }
}

// ---------------------------------------------------------------- K3: fused QK->exp->P + PV, DMA staging
// grid (32 i-tiles, 4 j-chunks, 8 heads) = 1024 blocks; LDS 40960 B -> 4 blocks/CU
// launch_bounds(256,2): 256-VGPR budget so the ~110-reg body does NOT spill
// (R8: bounds(256,4) made the allocator pick 64 regs -> ~138 MB scratch traffic).
__global__ __launch_bounds__(256, 2) void k_attn9(const u16* __restrict__ Qn,
                                                  const u16* __restrict__ Kn,
                                                  const u16* __restrict__ Vt,
                                                  const float* __restrict__ cls,
                                                  u16* __restrict__ P,
                                                  float* __restrict__ Spart,
                                                  u16* __restrict__ Xpart) {
    __shared__ u16 Kf[8192];  // QK B-frags, 16 groups: slot ((tn*4+kt)*64+lane)*8
    __shared__ u16 Vf[8192];  // PV B-frags, 16 groups: slot ((n*2+ks)*64+lane)*8
    __shared__ u16 Et[4096];  // e tile 64x64 bf16, XOR-chunk swizzled
    const int h = blockIdx.z;
    const int jc = blockIdx.y;
    const int i0 = blockIdx.x * 64;
    const int jbase = jc * 512;
    const int tid = threadIdx.x, lane = tid & 63, wid = tid >> 6;
    const int q = lane >> 4, l16 = lane & 15;
    const int wm = wid >> 1, wn = wid & 1;

    // resident Q fragments (i range: wm*32 .. +31)
    short8 af[2][4];
#pragma unroll
    for (int m = 0; m < 2; m++)
#pragma unroll
        for (int kt = 0; kt < 4; kt++)
            af[m][kt] = *(const short8*)&Qn[(long long)(i0 + wm * 32 + m * 16 + l16) * CDIM +
                                            h * HD + kt * 32 + q * 8];
    float cls_i[2][4];
#pragma unroll
    for (int m = 0; m < 2; m++)
#pragma unroll
        for (int r = 0; r < 4; r++)
            cls_i[m][r] = cls[i0 + wm * 32 + m * 16 + q * 4 + r] - 0.1f;

    // DMA gather sources: wave `wid` owns groups wid*4..wid*4+3 for Kf and Vf.
    const u16* ksrc[4];
    const u16* vsrc[4];
#pragma unroll
    for (int t = 0; t < 4; t++) {
        int g = wid * 4 + t;
        int tn = g >> 2, kt = g & 3;
        ksrc[t] = &Kn[(long long)(jbase + tn * 16 + l16) * CDIM + h * HD + kt * 32 + q * 8];
        int n = g >> 1, ks = g & 1;
        vsrc[t] = &Vt[(long long)(h * HD + n * 16 + l16) * NTOK + jbase + (ks * 4 + q) * 8];
    }

    f32x4 zero4 = {0.f, 0.f, 0.f, 0.f};
    f32x4 pv[2][4];
#pragma unroll
    for (int m = 0; m < 2; m++)
#pragma unroll
        for (int n = 0; n < 4; n++) pv[m][n] = zero4;
    float sums[2][4] = {{0.f, 0.f, 0.f, 0.f}, {0.f, 0.f, 0.f, 0.f}};

    for (int jt = 0; jt < 8; ++jt) {
        const int j0 = jbase + jt * 64;
        __syncthreads();  // previous-iter consumers done with Kf/Vf/Et
#pragma unroll
        for (int t = 0; t < 4; t++) {
            int g = wid * 4 + t;
            gld_lds16(ksrc[t], &Kf[(g * 64 + lane) * 8]);
            gld_lds16(vsrc[t], &Vf[(g * 64 + lane) * 8]);
            ksrc[t] += 64 * CDIM;
            vsrc[t] += 64;
        }
        __syncthreads();  // drains DMA (vmcnt) + LDS visible
        // QK -> e -> Et (+ row sums)
#pragma unroll
        for (int tn = 0; tn < 2; tn++) {
            int tng = wn * 2 + tn;
            short8 bfr[4];
#pragma unroll
            for (int kt = 0; kt < 4; kt++)
                bfr[kt] = *(const short8*)&Kf[((tng * 4 + kt) * 64 + lane) * 8];
            int j = j0 + tng * 16 + l16;
            float cj = cls[j];
            float sc = 25.f * cj;
#pragma unroll
            for (int m = 0; m < 2; m++) {
                f32x4 acc = zero4;
#pragma unroll
                for (int kt = 0; kt < 4; kt++)
                    acc = __builtin_amdgcn_mfma_f32_16x16x32_bf16(af[m][kt], bfr[kt],
                                                                  acc, 0, 0, 0);
                int ibase = wm * 32 + m * 16 + q * 4;
#pragma unroll
                for (int r = 0; r < 4; r++) {
                    float mk = (cj > cls_i[m][r]) ? 1.f : 0.f;
                    float e = __expf(acc[r] * sc * mk);
                    sums[m][r] += e;
                    int il = ibase + r;
                    int jl = tng * 16 + l16;
                    Et[il * 64 + ((((jl >> 3) ^ (il & 7)) << 3) | (jl & 7))] = f2bf(e);
                }
            }
        }
        __syncthreads();
        {   // coalesced P store from Et
            int il = tid >> 2, c = tid & 3;
            int x = il & 7;
            short8 e0 = *(const short8*)&Et[il * 64 + (((2 * c) ^ x) << 3)];
            short8 e1 = *(const short8*)&Et[il * 64 + (((2 * c + 1) ^ x) << 3)];
            u16* dst = &P[((long long)(h * NTOK + i0 + il)) * NTOK + j0 + c * 16];
            *(short8*)&dst[0] = e0;
            *(short8*)&dst[8] = e1;
        }
        // PV: A from Et (swizzled), B from Vf; out tile i(64) x d(128)
#pragma unroll
        for (int ks = 0; ks < 2; ks++) {
            short8 a2[2];
#pragma unroll
            for (int m2 = 0; m2 < 2; m2++) {
                int il = wm * 32 + m2 * 16 + l16;
                int ch = ks * 4 + q;
                a2[m2] = *(const short8*)&Et[il * 64 + ((ch ^ (il & 7)) << 3)];
            }
#pragma unroll
            for (int n2 = 0; n2 < 4; n2++) {
                short8 b2 = *(const short8*)&Vf[(((wn * 4 + n2) * 2 + ks) * 64 + lane) * 8];
#pragma unroll
                for (int m2 = 0; m2 < 2; m2++)
                    pv[m2][n2] = __builtin_amdgcn_mfma_f32_16x16x32_bf16(
                        a2[m2], b2, pv[m2][n2], 0, 0, 0);
            }
        }
    }
    // row-sum partials (race-free: one writer per (wn,jc,h,row))
#pragma unroll
    for (int m = 0; m < 2; m++)
#pragma unroll
        for (int r = 0; r < 4; r++) {
            float s = sums[m][r];
            s += __shfl_xor(s, 1);
            s += __shfl_xor(s, 2);
            s += __shfl_xor(s, 4);
            s += __shfl_xor(s, 8);
            if (l16 == 0)
                Spart[((wn * 4 + jc) * NH + h) * NTOK + i0 + wm * 32 + m * 16 + q * 4 + r] = s;
        }
    // store PV partial to this jc's slab (bf16, plain stores, no atomics)
    u16* Xp = Xpart + (long long)jc * NTOK * CDIM;
#pragma unroll
    for (int m2 = 0; m2 < 2; m2++)
#pragma unroll
        for (int n2 = 0; n2 < 4; n2++)
#pragma unroll
            for (int r = 0; r < 4; r++) {
                int i = i0 + wm * 32 + m2 * 16 + q * 4 + r;
                int d = wn * 64 + n2 * 16 + l16;
                Xp[(long long)i * CDIM + h * HD + d] = f2bf(pv[m2][n2][r]);
            }
}

// ---------------------------------------------------------------- K4: merged epilogue: x=(sum Xpart)/S  and  output2
__global__ __launch_bounds__(256) void k_epi(const u16* __restrict__ Xpart,
                                             const float* __restrict__ Spart,
                                             const u16* __restrict__ P,
                                             const unsigned char* __restrict__ mask,
                                             float* __restrict__ out,
                                             float* __restrict__ out2) {
    __shared__ float red[256];
    __shared__ float sArr[NH];
    const int i = blockIdx.x;
    const int t = threadIdx.x;
    if (t < NH) {
        float s = 0.f;
#pragma unroll
        for (int g = 0; g < 8; g++) s += Spart[(g * NH + t) * NTOK + i];
        sArr[t] = s;
    }
    __syncthreads();
    // ---- part A: x row i (1024 cols, 4 per thread)
    {
        int c = t * 4;
        int h = c >> 7;
        float acc[4] = {0.f, 0.f, 0.f, 0.f};
#pragma unroll
        for (int jc = 0; jc < 4; jc++) {
            short4v v = *(const short4v*)&Xpart[(long long)jc * NTOK * CDIM +
                                                (long long)i * CDIM + c];
#pragma unroll
            for (int k = 0; k < 4; k++) acc[k] += bf2f((u16)v[k]);
        }
        float invs = 1.f / sArr[h];
        float4 o;
        o.x = acc[0] * invs; o.y = acc[1] * invs; o.z = acc[2] * invs; o.w = acc[3] * invs;
        *(float4*)&out[(long long)i * 2048 + c] = o;
    }
    // ---- part B: output2 row i (2048 cols, 8 per thread)
    float invS[NH];
#pragma unroll
    for (int h = 0; h < NH; h++) invS[h] = 1.f / (8.f * sArr[h]);
    const int c0 = t * 8;
    float a[8] = {0.f, 0.f, 0.f, 0.f, 0.f, 0.f, 0.f, 0.f};
#pragma unroll
    for (int h = 0; h < NH; h++) {
        short8 p = *(const short8*)&P[((long long)h * NTOK + i) * NTOK + c0];
#pragma unroll
        for (int k = 0; k < 8; k++) a[k] += bf2f((u16)p[k]) * invS[h];
    }
    const unsigned char* mrow = mask + (long long)i * NTOK + c0;
    float e[8];
    unsigned char mk[8];
    float part = 0.f;
#pragma unroll
    for (int k = 0; k < 8; k++) {
        e[k] = __expf(a[k]);
        mk[k] = mrow[k];
        if (mk[k]) part += e[k];
    }
    red[t] = part;
    __syncthreads();
    for (int s = 128; s > 0; s >>= 1) {
        if (t < s) red[t] += red[t + s];
        __syncthreads();
    }
    float invT = 1.f / red[0];
    float o[8];
#pragma unroll
    for (int k = 0; k < 8; k++) o[k] = mk[k] ? e[k] * invT : 0.f;
    float4 o0, o1;
    o0.x = o[0]; o0.y = o[1]; o0.z = o[2]; o0.w = o[3];
    o1.x = o[4]; o1.y = o[5]; o1.z = o[6]; o1.w = o[7];
    float* dst = out2 + (long long)i * NTOK + c0;
    *(float4*)dst = o0;
    *(float4*)(dst + 4) = o1;
}

// ---------------------------------------------------------------- launcher
extern "C" void kernel_launch(void* const* d_in, const int* in_sizes, int n_in,
                              void* d_out, int out_size, void* d_ws,
                              size_t ws_size, hipStream_t stream) {
    (void)in_sizes; (void)n_in; (void)out_size; (void)ws_size;
    const float* x = (const float*)d_in[0];
    const float* cls = (const float*)d_in[1];
    // d_in[2] = fg_score: unused by the reference
    const float* Wq = (const float*)d_in[3];
    float* out = (float*)d_out;
    char* ws = (char*)d_ws;

    // Region [0, 23068672): early buffers (Xb/Wb dead after QKV gemm; QKVb dead
    // after k_vt) overlaid with Xpart/Spart (written only by k_attn9 afterwards).
    u16* Xb = (u16*)(ws + 0);                      //  4 MB  [2048,1024]
    u16* Wb = (u16*)(ws + 4194304);                //  6 MB  [3072,1024]
    u16* QKVb = (u16*)(ws + 10485760);             // 12.6MB [2048,3072]
    u16* Xpart = (u16*)(ws + 0);                   // 16 MB  [4][2048,1024] bf16 PV partials
    float* Spart = (float*)(ws + 16777216);        // 512 KB [8][8,2048] row-sum partials
    u16* Qn = (u16*)(ws + 23068672);               //  4 MB
    u16* Kn = (u16*)(ws + 27262976);               //  4 MB
    u16* Vn = (u16*)(ws + 31457280);               //  4 MB
    u16* Vt = (u16*)(ws + 35651584);               //  4 MB  [1024,2048]
    unsigned char* mask = (unsigned char*)(ws + 39845888);  // 4 MB [2048,2048]
    u16* P = (u16*)(ws + 44040192);                // 67 MB [8,2048,2048]

    // 1. cast x and W to bf16
    k_cast<<<1024, 256, 0, stream>>>(x, Wq, Xb, Wb);

    // 2. QKV = Xb @ Wb^T -> bf16 [2048,3072]  (DMA GEMM)
    k_gemm16<0><<<dim3(C3 / 128, NTOK / 128), 256, 0, stream>>>(
        Xb, Wb, QKVb, CDIM, CDIM, CDIM, C3, 1.f);

    // 3. normalize q/k/v, write x_ori
    k_norm<<<NTOK, 256, 0, stream>>>(QKVb, Qn, Kn, Vn, out);

    // 3b. Vt = v^T (raw v), tiled transpose
    k_vt<<<dim3(NTOK / 64, CDIM / 64), 256, 0, stream>>>(QKVb, Vt);

    // 4. sim mask = (Vn @ Vn^T / 8 > 0.75) -> u8, symmetric (lower blocks only)
    k_gemm16<2><<<dim3(16, 16), 256, 0, stream>>>(
        Vn, Vn, mask, CDIM, CDIM, CDIM, NTOK, 0.125f);

    // 5. fused logits+exp -> P, partial row sums, partial PV -> Xpart
    k_attn9<<<dim3(32, 4, NH), 256, 0, stream>>>(Qn, Kn, Vt, cls, P, Spart, Xpart);

    // 6. merged epilogue: x and output2
    k_epi<<<NTOK, 256, 0, stream>>>(Xpart, Spart, P, mask, out,
                                    out + (long long)NTOK * 2048);
}

// Round 10
// 223.465 us; speedup vs baseline: 1.1476x; 1.0388x over previous
//
#include <hip/hip_runtime.h>
#include <cstdint>

typedef unsigned short u16;
typedef __attribute__((ext_vector_type(8))) short short8;
typedef __attribute__((ext_vector_type(4))) short short4v;
typedef __attribute__((ext_vector_type(4))) float f32x4;

#define NTOK 2048
#define CDIM 1024
#define C3   3072
#define NH   8
#define HD   128

__device__ __forceinline__ float bf2f(u16 u) {
    return __uint_as_float(((unsigned)u) << 16);
}
__device__ __forceinline__ u16 f2bf(float f) {
    unsigned u = __float_as_uint(f);
    u += 0x7fffu + ((u >> 16) & 1u);
    return (u16)(u >> 16);
}
// async 16B global->LDS DMA; LDS dest must be wave-uniform base + lane*16
__device__ __forceinline__ void gld_lds16(const u16* g, u16* l) {
    __builtin_amdgcn_global_load_lds(
        (__attribute__((address_space(1))) void*)(u16*)g,
        (__attribute__((address_space(3))) void*)l, 16, 0, 0);
}

// ---------------------------------------------------------------- K0: f32->bf16
__global__ __launch_bounds__(256) void k_cast(const float* __restrict__ x,
                                              const float* __restrict__ w,
                                              u16* __restrict__ xb,
                                              u16* __restrict__ wb) {
    int t = blockIdx.x * blockDim.x + threadIdx.x;
    int stride = gridDim.x * blockDim.x;
    for (int i = t; i < (NTOK * CDIM) / 4; i += stride) {
        float4 v = ((const float4*)x)[i];
        ushort4 o;
        o.x = f2bf(v.x); o.y = f2bf(v.y); o.z = f2bf(v.z); o.w = f2bf(v.w);
        ((ushort4*)xb)[i] = o;
    }
    for (int i = t; i < (C3 * CDIM) / 4; i += stride) {
        float4 v = ((const float4*)w)[i];
        ushort4 o;
        o.x = f2bf(v.x); o.y = f2bf(v.y); o.z = f2bf(v.z); o.w = f2bf(v.w);
        ((ushort4*)wb)[i] = o;
    }
}

// ---------------------------------------------------------------- K1: BK=64 DMA bf16 GEMM, C = A[M,K] @ B[N,K]^T
// 128x128 tile, LDS 32 KB, 32 MFMA per barrier-pair (half the barriers of BK=32).
// EPI 0: write bf16. EPI 2: symmetric u8 mask (bx<=by blocks only; writes both).
template <int EPI>
__global__ __launch_bounds__(256) void k_gemm64(const u16* __restrict__ A,
                                                const u16* __restrict__ B,
                                                void* __restrict__ Cv, int K,
                                                int lda, int ldb, int ldc,
                                                float scale) {
    if (EPI == 2 && blockIdx.x > blockIdx.y) return;  // symmetric: skip upper
    __shared__ u16 As[128 * 64];
    __shared__ u16 Bs[128 * 64];
    const int tid = threadIdx.x;
    const int lane = tid & 63;
    const int wid = tid >> 6;
    const int wm = wid >> 1, wn = wid & 1;
    const int q = lane >> 4, l16 = lane & 15;
    const int m0 = blockIdx.y * 128, n0 = blockIdx.x * 128;

    f32x4 zero4 = {0.f, 0.f, 0.f, 0.f};
    f32x4 acc[4][4];
#pragma unroll
    for (int i = 0; i < 4; i++)
#pragma unroll
        for (int j = 0; j < 4; j++) acc[i][j] = zero4;

    // 1024 slots per matrix: slot s -> row s>>3, 8-u16 chunk s&7.
    // Each thread owns slots tid + {0,256,512,768}: dest = base + lane*16 per wave.
    const u16* aP[4];
    const u16* bP[4];
#pragma unroll
    for (int t = 0; t < 4; t++) {
        int s = tid + t * 256;
        int r = s >> 3, c = (s & 7) * 8;
        aP[t] = &A[(long long)(m0 + r) * lda + c];
        bP[t] = &B[(long long)(n0 + r) * ldb + c];
    }

    for (int k0 = 0; k0 < K; k0 += 64) {
        __syncthreads();
#pragma unroll
        for (int t = 0; t < 4; t++) {
            int s = tid + t * 256;
            gld_lds16(aP[t] + k0, &As[s * 8]);
            gld_lds16(bP[t] + k0, &Bs[s * 8]);
        }
        __syncthreads();
#pragma unroll
        for (int ks = 0; ks < 2; ks++) {
            short8 af[4], bfr[4];
#pragma unroll
            for (int tm = 0; tm < 4; tm++)
                af[tm] = *(const short8*)&As[(wm * 64 + tm * 16 + l16) * 64 + ks * 32 + q * 8];
#pragma unroll
            for (int tn = 0; tn < 4; tn++)
                bfr[tn] = *(const short8*)&Bs[(wn * 64 + tn * 16 + l16) * 64 + ks * 32 + q * 8];
#pragma unroll
            for (int tm = 0; tm < 4; tm++)
#pragma unroll
                for (int tn = 0; tn < 4; tn++)
                    acc[tm][tn] = __builtin_amdgcn_mfma_f32_16x16x32_bf16(
                        af[tm], bfr[tn], acc[tm][tn], 0, 0, 0);
        }
    }

#pragma unroll
    for (int tm = 0; tm < 4; tm++)
#pragma unroll
        for (int tn = 0; tn < 4; tn++)
#pragma unroll
            for (int r = 0; r < 4; r++) {
                int row = m0 + wm * 64 + tm * 16 + q * 4 + r;
                int col = n0 + wn * 64 + tn * 16 + l16;
                float v = acc[tm][tn][r];
                if (EPI == 0) {
                    ((u16*)Cv)[(long long)row * ldc + col] = f2bf(v);
                } else {
                    unsigned char b = (v * scale > 0.75f) ? 1 : 0;
                    ((unsigned char*)Cv)[(long long)row * ldc + col] = b;
                    ((unsigned char*)Cv)[(long long)col * ldc + row] = b;
                }
            }
}

// ---------------------------------------------------------------- K2: per-row L2 normalize q/k/v heads + x_ori (x8 vec)
__global__ __launch_bounds__(256) void k_norm(const u16* __restrict__ qkv,
                                              u16* __restrict__ Qn,
                                              u16* __restrict__ Kn,
                                              u16* __restrict__ Vn,
                                              float* __restrict__ out) {
    const int n = blockIdx.x;
    const int t = threadIdx.x;
    const int g16 = t >> 4;      // 0..15: 16-lane group
    const int l16 = t & 15;
    const int d0 = l16 * 8;
#pragma unroll
    for (int s = 0; s < 2; s++) {
        int row = s * 16 + g16;  // 0..31, need 0..23
        if (row < 24) {
            int which = row >> 3;  // 0=q 1=k 2=v
            int h = row & 7;
            const u16* src = qkv + (long long)n * C3 + which * CDIM + h * HD + d0;
            short8 v8 = *(const short8*)src;
            float f[8];
            float ss = 0.f;
#pragma unroll
            for (int k = 0; k < 8; k++) {
                f[k] = bf2f((u16)v8[k]);
                ss += f[k] * f[k];
            }
            ss += __shfl_xor(ss, 1);
            ss += __shfl_xor(ss, 2);
            ss += __shfl_xor(ss, 4);
            ss += __shfl_xor(ss, 8);
            float rn = rsqrtf(ss);
            u16* dst = (which == 0 ? Qn : which == 1 ? Kn : Vn) +
                       (long long)n * CDIM + h * HD + d0;
            short8 o8;
#pragma unroll
            for (int k = 0; k < 8; k++) o8[k] = (short)f2bf(f[k] * rn);
            *(short8*)dst = o8;
            if (which == 2) {
                float4 a, b;
                a.x = f[0]; a.y = f[1]; a.z = f[2]; a.w = f[3];
                b.x = f[4]; b.y = f[5]; b.z = f[6]; b.w = f[7];
                float* od = &out[(long long)n * 2048 + 1024 + h * HD + d0];
                *(float4*)od = a;
                *(float4*)(od + 4) = b;
            }
        }
    }
}

// ---------------------------------------------------------------- K2b: tiled transpose Vt[c][n] = v[n][c] (raw v)
__global__ __launch_bounds__(256) void k_vt(const u16* __restrict__ qkv,
                                            u16* __restrict__ Vt) {
    __shared__ u16 T[64][72];
    const int n0 = blockIdx.x * 64;
    const int c0 = blockIdx.y * 64;
    const int tid = threadIdx.x;
    {
        int nl = tid >> 2, cc = (tid & 3) * 16;
        const u16* src = &qkv[(long long)(n0 + nl) * C3 + 2 * CDIM + c0 + cc];
        *(short8*)&T[nl][cc] = *(const short8*)&src[0];
        *(short8*)&T[nl][cc + 8] = *(const short8*)&src[8];
    }
    __syncthreads();
    {
        int cl = tid >> 2, nc = (tid & 3) * 16;
        ushort va[16];
#pragma unroll
        for (int i = 0; i < 16; i++) va[i] = T[nc + i][cl];
        u16* dst = &Vt[(long long)(c0 + cl) * NTOK + n0 + nc];
        *(short8*)&dst[0] = *(short8*)&va[0];
        *(short8*)&dst[8] = *(short8*)&va[8];
    }
}

// ---------------------------------------------------------------- K3: fused QK->exp->P + PV, DMA staging
// EXACT R7 configuration (66 us measured): bounds(256,4), Kf/Vf declared 16384
// (LDS 73728 -> 2 blocks/CU) -> compiler allocates 108 VGPRs, no spill, best
// scheduling. R8 (LDS 40960, same bounds) -> 64 regs + spill; R9 (bounds(256,2))
// -> 80 regs, 76 us. Codegen quality, not occupancy, is binding. DO NOT TOUCH.
__global__ __launch_bounds__(256, 4) void k_attn7(const u16* __restrict__ Qn,
                                                  const u16* __restrict__ Kn,
                                                  const u16* __restrict__ Vt,
                                                  const float* __restrict__ cls,
                                                  u16* __restrict__ P,
                                                  float* __restrict__ Spart,
                                                  u16* __restrict__ Xpart) {
    __shared__ u16 Kf[16384];  // QK B-frags, 16 groups: slot ((tn*4+kt)*64+lane)*8
    __shared__ u16 Vf[16384];  // PV B-frags, 16 groups: slot ((n*2+ks)*64+lane)*8
    __shared__ u16 Et[4096];   // e tile 64x64 bf16, XOR-chunk swizzled
    const int h = blockIdx.z;
    const int jc = blockIdx.y;
    const int i0 = blockIdx.x * 64;
    const int jbase = jc * 512;
    const int tid = threadIdx.x, lane = tid & 63, wid = tid >> 6;
    const int q = lane >> 4, l16 = lane & 15;
    const int wm = wid >> 1, wn = wid & 1;

    // resident Q fragments (i range: wm*32 .. +31)
    short8 af[2][4];
#pragma unroll
    for (int m = 0; m < 2; m++)
#pragma unroll
        for (int kt = 0; kt < 4; kt++)
            af[m][kt] = *(const short8*)&Qn[(long long)(i0 + wm * 32 + m * 16 + l16) * CDIM +
                                            h * HD + kt * 32 + q * 8];
    float cls_i[2][4];
#pragma unroll
    for (int m = 0; m < 2; m++)
#pragma unroll
        for (int r = 0; r < 4; r++)
            cls_i[m][r] = cls[i0 + wm * 32 + m * 16 + q * 4 + r] - 0.1f;

    // DMA gather sources: wave `wid` owns groups wid*4..wid*4+3 for Kf and Vf.
    const u16* ksrc[4];
    const u16* vsrc[4];
#pragma unroll
    for (int t = 0; t < 4; t++) {
        int g = wid * 4 + t;
        int tn = g >> 2, kt = g & 3;
        ksrc[t] = &Kn[(long long)(jbase + tn * 16 + l16) * CDIM + h * HD + kt * 32 + q * 8];
        int n = g >> 1, ks = g & 1;
        vsrc[t] = &Vt[(long long)(h * HD + n * 16 + l16) * NTOK + jbase + (ks * 4 + q) * 8];
    }

    f32x4 zero4 = {0.f, 0.f, 0.f, 0.f};
    f32x4 pv[2][4];
#pragma unroll
    for (int m = 0; m < 2; m++)
#pragma unroll
        for (int n = 0; n < 4; n++) pv[m][n] = zero4;
    float sums[2][4] = {{0.f, 0.f, 0.f, 0.f}, {0.f, 0.f, 0.f, 0.f}};

    for (int jt = 0; jt < 8; ++jt) {
        const int j0 = jbase + jt * 64;
        __syncthreads();  // previous-iter consumers done with Kf/Vf/Et
#pragma unroll
        for (int t = 0; t < 4; t++) {
            int g = wid * 4 + t;
            gld_lds16(ksrc[t], &Kf[(g * 64 + lane) * 8]);
            gld_lds16(vsrc[t], &Vf[(g * 64 + lane) * 8]);
            ksrc[t] += 64 * CDIM;
            vsrc[t] += 64;
        }
        __syncthreads();  // drains DMA (vmcnt) + LDS visible
        // QK -> e -> Et (+ row sums)
#pragma unroll
        for (int tn = 0; tn < 2; tn++) {
            int tng = wn * 2 + tn;
            short8 bfr[4];
#pragma unroll
            for (int kt = 0; kt < 4; kt++)
                bfr[kt] = *(const short8*)&Kf[((tng * 4 + kt) * 64 + lane) * 8];
            int j = j0 + tng * 16 + l16;
            float cj = cls[j];
            float sc = 25.f * cj;
#pragma unroll
            for (int m = 0; m < 2; m++) {
                f32x4 acc = zero4;
#pragma unroll
                for (int kt = 0; kt < 4; kt++)
                    acc = __builtin_amdgcn_mfma_f32_16x16x32_bf16(af[m][kt], bfr[kt],
                                                                  acc, 0, 0, 0);
                int ibase = wm * 32 + m * 16 + q * 4;
#pragma unroll
                for (int r = 0; r < 4; r++) {
                    float mk = (cj > cls_i[m][r]) ? 1.f : 0.f;
                    float e = __expf(acc[r] * sc * mk);
                    sums[m][r] += e;
                    int il = ibase + r;
                    int jl = tng * 16 + l16;
                    Et[il * 64 + ((((jl >> 3) ^ (il & 7)) << 3) | (jl & 7))] = f2bf(e);
                }
            }
        }
        __syncthreads();
        {   // coalesced P store from Et
            int il = tid >> 2, c = tid & 3;
            int x = il & 7;
            short8 e0 = *(const short8*)&Et[il * 64 + (((2 * c) ^ x) << 3)];
            short8 e1 = *(const short8*)&Et[il * 64 + (((2 * c + 1) ^ x) << 3)];
            u16* dst = &P[((long long)(h * NTOK + i0 + il)) * NTOK + j0 + c * 16];
            *(short8*)&dst[0] = e0;
            *(short8*)&dst[8] = e1;
        }
        // PV: A from Et (swizzled), B from Vf; out tile i(64) x d(128)
#pragma unroll
        for (int ks = 0; ks < 2; ks++) {
            short8 a2[2];
#pragma unroll
            for (int m2 = 0; m2 < 2; m2++) {
                int il = wm * 32 + m2 * 16 + l16;
                int ch = ks * 4 + q;
                a2[m2] = *(const short8*)&Et[il * 64 + ((ch ^ (il & 7)) << 3)];
            }
#pragma unroll
            for (int n2 = 0; n2 < 4; n2++) {
                short8 b2 = *(const short8*)&Vf[(((wn * 4 + n2) * 2 + ks) * 64 + lane) * 8];
#pragma unroll
                for (int m2 = 0; m2 < 2; m2++)
                    pv[m2][n2] = __builtin_amdgcn_mfma_f32_16x16x32_bf16(
                        a2[m2], b2, pv[m2][n2], 0, 0, 0);
            }
        }
    }
    // row-sum partials (race-free: one writer per (wn,jc,h,row))
#pragma unroll
    for (int m = 0; m < 2; m++)
#pragma unroll
        for (int r = 0; r < 4; r++) {
            float s = sums[m][r];
            s += __shfl_xor(s, 1);
            s += __shfl_xor(s, 2);
            s += __shfl_xor(s, 4);
            s += __shfl_xor(s, 8);
            if (l16 == 0)
                Spart[((wn * 4 + jc) * NH + h) * NTOK + i0 + wm * 32 + m * 16 + q * 4 + r] = s;
        }
    // store PV partial to this jc's slab (bf16, plain stores, no atomics)
    u16* Xp = Xpart + (long long)jc * NTOK * CDIM;
#pragma unroll
    for (int m2 = 0; m2 < 2; m2++)
#pragma unroll
        for (int n2 = 0; n2 < 4; n2++)
#pragma unroll
            for (int r = 0; r < 4; r++) {
                int i = i0 + wm * 32 + m2 * 16 + q * 4 + r;
                int d = wn * 64 + n2 * 16 + l16;
                Xp[(long long)i * CDIM + h * HD + d] = f2bf(pv[m2][n2][r]);
            }
}

// ---------------------------------------------------------------- K4: merged epilogue: x=(sum Xpart)/S  and  output2
__global__ __launch_bounds__(256) void k_epi(const u16* __restrict__ Xpart,
                                             const float* __restrict__ Spart,
                                             const u16* __restrict__ P,
                                             const unsigned char* __restrict__ mask,
                                             float* __restrict__ out,
                                             float* __restrict__ out2) {
    __shared__ float red[256];
    __shared__ float sArr[NH];
    const int i = blockIdx.x;
    const int t = threadIdx.x;
    if (t < NH) {
        float s = 0.f;
#pragma unroll
        for (int g = 0; g < 8; g++) s += Spart[(g * NH + t) * NTOK + i];
        sArr[t] = s;
    }
    __syncthreads();
    // ---- part A: x row i (1024 cols, 4 per thread)
    {
        int c = t * 4;
        int h = c >> 7;
        float acc[4] = {0.f, 0.f, 0.f, 0.f};
#pragma unroll
        for (int jc = 0; jc < 4; jc++) {
            short4v v = *(const short4v*)&Xpart[(long long)jc * NTOK * CDIM +
                                                (long long)i * CDIM + c];
#pragma unroll
            for (int k = 0; k < 4; k++) acc[k] += bf2f((u16)v[k]);
        }
        float invs = 1.f / sArr[h];
        float4 o;
        o.x = acc[0] * invs; o.y = acc[1] * invs; o.z = acc[2] * invs; o.w = acc[3] * invs;
        *(float4*)&out[(long long)i * 2048 + c] = o;
    }
    // ---- part B: output2 row i (2048 cols, 8 per thread)
    float invS[NH];
#pragma unroll
    for (int h = 0; h < NH; h++) invS[h] = 1.f / (8.f * sArr[h]);
    const int c0 = t * 8;
    float a[8] = {0.f, 0.f, 0.f, 0.f, 0.f, 0.f, 0.f, 0.f};
#pragma unroll
    for (int h = 0; h < NH; h++) {
        short8 p = *(const short8*)&P[((long long)h * NTOK + i) * NTOK + c0];
#pragma unroll
        for (int k = 0; k < 8; k++) a[k] += bf2f((u16)p[k]) * invS[h];
    }
    const unsigned char* mrow = mask + (long long)i * NTOK + c0;
    float e[8];
    unsigned char mk[8];
    float part = 0.f;
#pragma unroll
    for (int k = 0; k < 8; k++) {
        e[k] = __expf(a[k]);
        mk[k] = mrow[k];
        if (mk[k]) part += e[k];
    }
    red[t] = part;
    __syncthreads();
    for (int s = 128; s > 0; s >>= 1) {
        if (t < s) red[t] += red[t + s];
        __syncthreads();
    }
    float invT = 1.f / red[0];
    float o[8];
#pragma unroll
    for (int k = 0; k < 8; k++) o[k] = mk[k] ? e[k] * invT : 0.f;
    float4 o0, o1;
    o0.x = o[0]; o0.y = o[1]; o0.z = o[2]; o0.w = o[3];
    o1.x = o[4]; o1.y = o[5]; o1.z = o[6]; o1.w = o[7];
    float* dst = out2 + (long long)i * NTOK + c0;
    *(float4*)dst = o0;
    *(float4*)(dst + 4) = o1;
}

// ---------------------------------------------------------------- launcher
extern "C" void kernel_launch(void* const* d_in, const int* in_sizes, int n_in,
                              void* d_out, int out_size, void* d_ws,
                              size_t ws_size, hipStream_t stream) {
    (void)in_sizes; (void)n_in; (void)out_size; (void)ws_size;
    const float* x = (const float*)d_in[0];
    const float* cls = (const float*)d_in[1];
    // d_in[2] = fg_score: unused by the reference
    const float* Wq = (const float*)d_in[3];
    float* out = (float*)d_out;
    char* ws = (char*)d_ws;

    // Region [0, 23068672): early buffers (Xb/Wb dead after QKV gemm; QKVb dead
    // after k_vt) overlaid with Xpart/Spart (written only by k_attn7 afterwards).
    u16* Xb = (u16*)(ws + 0);                      //  4 MB  [2048,1024]
    u16* Wb = (u16*)(ws + 4194304);                //  6 MB  [3072,1024]
    u16* QKVb = (u16*)(ws + 10485760);             // 12.6MB [2048,3072]
    u16* Xpart = (u16*)(ws + 0);                   // 16 MB  [4][2048,1024] bf16 PV partials
    float* Spart = (float*)(ws + 16777216);        // 512 KB [8][8,2048] row-sum partials
    u16* Qn = (u16*)(ws + 23068672);               //  4 MB
    u16* Kn = (u16*)(ws + 27262976);               //  4 MB
    u16* Vn = (u16*)(ws + 31457280);               //  4 MB
    u16* Vt = (u16*)(ws + 35651584);               //  4 MB  [1024,2048]
    unsigned char* mask = (unsigned char*)(ws + 39845888);  // 4 MB [2048,2048]
    u16* P = (u16*)(ws + 44040192);                // 67 MB [8,2048,2048]

    // 1. cast x and W to bf16
    k_cast<<<1024, 256, 0, stream>>>(x, Wq, Xb, Wb);

    // 2. QKV = Xb @ Wb^T -> bf16 [2048,3072]  (BK=64 DMA GEMM)
    k_gemm64<0><<<dim3(C3 / 128, NTOK / 128), 256, 0, stream>>>(
        Xb, Wb, QKVb, CDIM, CDIM, CDIM, C3, 1.f);

    // 3. normalize q/k/v, write x_ori
    k_norm<<<NTOK, 256, 0, stream>>>(QKVb, Qn, Kn, Vn, out);

    // 3b. Vt = v^T (raw v), tiled transpose
    k_vt<<<dim3(NTOK / 64, CDIM / 64), 256, 0, stream>>>(QKVb, Vt);

    // 4. sim mask = (Vn @ Vn^T / 8 > 0.75) -> u8, symmetric (lower blocks only)
    k_gemm64<2><<<dim3(16, 16), 256, 0, stream>>>(
        Vn, Vn, mask, CDIM, CDIM, CDIM, NTOK, 0.125f);

    // 5. fused logits+exp -> P, partial row sums, partial PV -> Xpart
    k_attn7<<<dim3(32, 4, NH), 256, 0, stream>>>(Qn, Kn, Vt, cls, P, Spart, Xpart);

    // 6. merged epilogue: x and output2
    k_epi<<<NTOK, 256, 0, stream>>>(Xpart, Spart, P, mask, out,
                                    out + (long long)NTOK * 2048);
}

// Round 11
// 219.653 us; speedup vs baseline: 1.1676x; 1.0174x over previous
//
#include <hip/hip_runtime.h>
#include <cstdint>

typedef unsigned short u16;
typedef __attribute__((ext_vector_type(8))) short short8;
typedef __attribute__((ext_vector_type(4))) short short4v;
typedef __attribute__((ext_vector_type(4))) float f32x4;

#define NTOK 2048
#define CDIM 1024
#define C3   3072
#define NH   8
#define HD   128

__device__ __forceinline__ float bf2f(u16 u) {
    return __uint_as_float(((unsigned)u) << 16);
}
__device__ __forceinline__ u16 f2bf(float f) {
    unsigned u = __float_as_uint(f);
    u += 0x7fffu + ((u >> 16) & 1u);
    return (u16)(u >> 16);
}
// async 16B global->LDS DMA; LDS dest must be wave-uniform base + lane*16
__device__ __forceinline__ void gld_lds16(const u16* g, u16* l) {
    __builtin_amdgcn_global_load_lds(
        (__attribute__((address_space(1))) void*)(u16*)g,
        (__attribute__((address_space(3))) void*)l, 16, 0, 0);
}

// ---------------------------------------------------------------- K0: f32->bf16
__global__ __launch_bounds__(256) void k_cast(const float* __restrict__ x,
                                              const float* __restrict__ w,
                                              u16* __restrict__ xb,
                                              u16* __restrict__ wb) {
    int t = blockIdx.x * blockDim.x + threadIdx.x;
    int stride = gridDim.x * blockDim.x;
    for (int i = t; i < (NTOK * CDIM) / 4; i += stride) {
        float4 v = ((const float4*)x)[i];
        ushort4 o;
        o.x = f2bf(v.x); o.y = f2bf(v.y); o.z = f2bf(v.z); o.w = f2bf(v.w);
        ((ushort4*)xb)[i] = o;
    }
    for (int i = t; i < (C3 * CDIM) / 4; i += stride) {
        float4 v = ((const float4*)w)[i];
        ushort4 o;
        o.x = f2bf(v.x); o.y = f2bf(v.y); o.z = f2bf(v.z); o.w = f2bf(v.w);
        ((ushort4*)wb)[i] = o;
    }
}

// ---------------------------------------------------------------- K1: fused QKV GEMM + norm/x_ori/Vt epilogue
// grid (24 head-slices, 16 m-tiles). Each block's 128-col tile IS one full
// head-slice, so the per-row L2 norm is computed from the block's own acc.
// Eliminates QKVb, k_norm, k_vt (2 dispatches + ~38 MB HBM round-trips).
__global__ __launch_bounds__(256) void k_qkvn(const u16* __restrict__ A,
                                              const u16* __restrict__ B,
                                              u16* __restrict__ Qn,
                                              u16* __restrict__ Kn,
                                              u16* __restrict__ Vn,
                                              u16* __restrict__ Vt,
                                              float* __restrict__ out) {
    __shared__ u16 lds[128 * 136];   // GEMM: As=lds[0:8192], Bs=lds[8192:16384]; epi: T[128][136]
    __shared__ float rowssq[128][2];
    u16* As = lds;
    u16* Bs = lds + 128 * 64;
    const int tid = threadIdx.x;
    const int lane = tid & 63;
    const int wid = tid >> 6;
    const int wm = wid >> 1, wn = wid & 1;
    const int q = lane >> 4, l16 = lane & 15;
    const int s = blockIdx.x;            // head-slice 0..23
    const int which = s >> 3, h = s & 7; // 0=q 1=k 2=v
    const int m0 = blockIdx.y * 128, n0 = s * 128;

    f32x4 zero4 = {0.f, 0.f, 0.f, 0.f};
    f32x4 acc[4][4];
#pragma unroll
    for (int i = 0; i < 4; i++)
#pragma unroll
        for (int j = 0; j < 4; j++) acc[i][j] = zero4;

    const u16* aP[4];
    const u16* bP[4];
#pragma unroll
    for (int t = 0; t < 4; t++) {
        int sl = tid + t * 256;
        int r = sl >> 3, c = (sl & 7) * 8;
        aP[t] = &A[(long long)(m0 + r) * CDIM + c];
        bP[t] = &B[(long long)(n0 + r) * CDIM + c];
    }

    for (int k0 = 0; k0 < CDIM; k0 += 64) {
        __syncthreads();
#pragma unroll
        for (int t = 0; t < 4; t++) {
            int sl = tid + t * 256;
            gld_lds16(aP[t] + k0, &As[sl * 8]);
            gld_lds16(bP[t] + k0, &Bs[sl * 8]);
        }
        __syncthreads();
#pragma unroll
        for (int ks = 0; ks < 2; ks++) {
            short8 af[4], bfr[4];
#pragma unroll
            for (int tm = 0; tm < 4; tm++)
                af[tm] = *(const short8*)&As[(wm * 64 + tm * 16 + l16) * 64 + ks * 32 + q * 8];
#pragma unroll
            for (int tn = 0; tn < 4; tn++)
                bfr[tn] = *(const short8*)&Bs[(wn * 64 + tn * 16 + l16) * 64 + ks * 32 + q * 8];
#pragma unroll
            for (int tm = 0; tm < 4; tm++)
#pragma unroll
                for (int tn = 0; tn < 4; tn++)
                    acc[tm][tn] = __builtin_amdgcn_mfma_f32_16x16x32_bf16(
                        af[tm], bfr[tn], acc[tm][tn], 0, 0, 0);
        }
    }

    __syncthreads();  // all LDS reads done; lds reusable, rowssq writable
    // per-row sum of squares: this wave's 64-col half, then cross-wave via LDS
#pragma unroll
    for (int tm = 0; tm < 4; tm++)
#pragma unroll
        for (int r = 0; r < 4; r++) {
            float p = 0.f;
#pragma unroll
            for (int tn = 0; tn < 4; tn++) p += acc[tm][tn][r] * acc[tm][tn][r];
            p += __shfl_xor(p, 1);
            p += __shfl_xor(p, 2);
            p += __shfl_xor(p, 4);
            p += __shfl_xor(p, 8);
            if (l16 == 0) rowssq[wm * 64 + tm * 16 + q * 4 + r][wn] = p;
        }
    __syncthreads();
    float rinv[4][4];
#pragma unroll
    for (int tm = 0; tm < 4; tm++)
#pragma unroll
        for (int r = 0; r < 4; r++) {
            int rl = wm * 64 + tm * 16 + q * 4 + r;
            rinv[tm][r] = rsqrtf(rowssq[rl][0] + rowssq[rl][1]);
        }
    // normalized bf16 store to Qn/Kn/Vn
    u16* dstBase = (which == 0 ? Qn : which == 1 ? Kn : Vn);
#pragma unroll
    for (int tm = 0; tm < 4; tm++)
#pragma unroll
        for (int tn = 0; tn < 4; tn++)
#pragma unroll
            for (int r = 0; r < 4; r++) {
                int rl = wm * 64 + tm * 16 + q * 4 + r;
                int d = wn * 64 + tn * 16 + l16;
                dstBase[(long long)(m0 + rl) * CDIM + h * HD + d] =
                    f2bf(acc[tm][tn][r] * rinv[tm][r]);
            }
    if (which == 2) {
        // x_ori (raw f32) + stage raw bf16 into T for the Vt transpose
#pragma unroll
        for (int tm = 0; tm < 4; tm++)
#pragma unroll
            for (int tn = 0; tn < 4; tn++)
#pragma unroll
                for (int r = 0; r < 4; r++) {
                    int rl = wm * 64 + tm * 16 + q * 4 + r;
                    int d = wn * 64 + tn * 16 + l16;
                    float v = acc[tm][tn][r];
                    out[(long long)(m0 + rl) * 2048 + 1024 + h * HD + d] = v;
                    lds[rl * 136 + d] = f2bf(v);
                }
        __syncthreads();
        // coalesced Vt store: Vt[h*HD+drow][m0..m0+127]
#pragma unroll
        for (int p = 0; p < 2; p++) {
            int drow = p * 64 + (tid >> 2);
            int nc = (tid & 3) * 32;
            u16 buf[32];
#pragma unroll
            for (int i = 0; i < 32; i++) buf[i] = lds[(nc + i) * 136 + drow];
            u16* dst = &Vt[(long long)(h * HD + drow) * NTOK + m0 + nc];
            *(short8*)&dst[0] = *(short8*)&buf[0];
            *(short8*)&dst[8] = *(short8*)&buf[8];
            *(short8*)&dst[16] = *(short8*)&buf[16];
            *(short8*)&dst[24] = *(short8*)&buf[24];
        }
    }
}

// ---------------------------------------------------------------- K1b: BK=64 DMA bf16 GEMM, symmetric u8 mask epilogue
__global__ __launch_bounds__(256) void k_gemm_mask(const u16* __restrict__ A,
                                                   const u16* __restrict__ B,
                                                   unsigned char* __restrict__ Cv,
                                                   int K, int lda, int ldb, int ldc,
                                                   float scale) {
    if (blockIdx.x > blockIdx.y) return;  // symmetric: skip upper
    __shared__ u16 As[128 * 64];
    __shared__ u16 Bs[128 * 64];
    const int tid = threadIdx.x;
    const int lane = tid & 63;
    const int wid = tid >> 6;
    const int wm = wid >> 1, wn = wid & 1;
    const int q = lane >> 4, l16 = lane & 15;
    const int m0 = blockIdx.y * 128, n0 = blockIdx.x * 128;

    f32x4 zero4 = {0.f, 0.f, 0.f, 0.f};
    f32x4 acc[4][4];
#pragma unroll
    for (int i = 0; i < 4; i++)
#pragma unroll
        for (int j = 0; j < 4; j++) acc[i][j] = zero4;

    const u16* aP[4];
    const u16* bP[4];
#pragma unroll
    for (int t = 0; t < 4; t++) {
        int s = tid + t * 256;
        int r = s >> 3, c = (s & 7) * 8;
        aP[t] = &A[(long long)(m0 + r) * lda + c];
        bP[t] = &B[(long long)(n0 + r) * ldb + c];
    }

    for (int k0 = 0; k0 < K; k0 += 64) {
        __syncthreads();
#pragma unroll
        for (int t = 0; t < 4; t++) {
            int s = tid + t * 256;
            gld_lds16(aP[t] + k0, &As[s * 8]);
            gld_lds16(bP[t] + k0, &Bs[s * 8]);
        }
        __syncthreads();
#pragma unroll
        for (int ks = 0; ks < 2; ks++) {
            short8 af[4], bfr[4];
#pragma unroll
            for (int tm = 0; tm < 4; tm++)
                af[tm] = *(const short8*)&As[(wm * 64 + tm * 16 + l16) * 64 + ks * 32 + q * 8];
#pragma unroll
            for (int tn = 0; tn < 4; tn++)
                bfr[tn] = *(const short8*)&Bs[(wn * 64 + tn * 16 + l16) * 64 + ks * 32 + q * 8];
#pragma unroll
            for (int tm = 0; tm < 4; tm++)
#pragma unroll
                for (int tn = 0; tn < 4; tn++)
                    acc[tm][tn] = __builtin_amdgcn_mfma_f32_16x16x32_bf16(
                        af[tm], bfr[tn], acc[tm][tn], 0, 0, 0);
        }
    }

#pragma unroll
    for (int tm = 0; tm < 4; tm++)
#pragma unroll
        for (int tn = 0; tn < 4; tn++)
#pragma unroll
            for (int r = 0; r < 4; r++) {
                int row = m0 + wm * 64 + tm * 16 + q * 4 + r;
                int col = n0 + wn * 64 + tn * 16 + l16;
                unsigned char b = (acc[tm][tn][r] * scale > 0.75f) ? 1 : 0;
                Cv[(long long)row * ldc + col] = b;
                Cv[(long long)col * ldc + row] = b;
            }
}

// ---------------------------------------------------------------- K3: fused QK->exp->P + PV, DMA staging
// EXACT R7 configuration (66 us measured): bounds(256,4), Kf/Vf declared 16384
// (LDS 73728 -> 2 blocks/CU) -> compiler allocates 108 VGPRs, no spill, best
// scheduling. R8 (LDS 40960, same bounds) -> 64 regs + spill; R9 (bounds(256,2))
// -> 80 regs, 76 us. Codegen quality, not occupancy, is binding. DO NOT TOUCH.
__global__ __launch_bounds__(256, 4) void k_attn7(const u16* __restrict__ Qn,
                                                  const u16* __restrict__ Kn,
                                                  const u16* __restrict__ Vt,
                                                  const float* __restrict__ cls,
                                                  u16* __restrict__ P,
                                                  float* __restrict__ Spart,
                                                  u16* __restrict__ Xpart) {
    __shared__ u16 Kf[16384];  // QK B-frags, 16 groups: slot ((tn*4+kt)*64+lane)*8
    __shared__ u16 Vf[16384];  // PV B-frags, 16 groups: slot ((n*2+ks)*64+lane)*8
    __shared__ u16 Et[4096];   // e tile 64x64 bf16, XOR-chunk swizzled
    const int h = blockIdx.z;
    const int jc = blockIdx.y;
    const int i0 = blockIdx.x * 64;
    const int jbase = jc * 512;
    const int tid = threadIdx.x, lane = tid & 63, wid = tid >> 6;
    const int q = lane >> 4, l16 = lane & 15;
    const int wm = wid >> 1, wn = wid & 1;

    // resident Q fragments (i range: wm*32 .. +31)
    short8 af[2][4];
#pragma unroll
    for (int m = 0; m < 2; m++)
#pragma unroll
        for (int kt = 0; kt < 4; kt++)
            af[m][kt] = *(const short8*)&Qn[(long long)(i0 + wm * 32 + m * 16 + l16) * CDIM +
                                            h * HD + kt * 32 + q * 8];
    float cls_i[2][4];
#pragma unroll
    for (int m = 0; m < 2; m++)
#pragma unroll
        for (int r = 0; r < 4; r++)
            cls_i[m][r] = cls[i0 + wm * 32 + m * 16 + q * 4 + r] - 0.1f;

    // DMA gather sources: wave `wid` owns groups wid*4..wid*4+3 for Kf and Vf.
    const u16* ksrc[4];
    const u16* vsrc[4];
#pragma unroll
    for (int t = 0; t < 4; t++) {
        int g = wid * 4 + t;
        int tn = g >> 2, kt = g & 3;
        ksrc[t] = &Kn[(long long)(jbase + tn * 16 + l16) * CDIM + h * HD + kt * 32 + q * 8];
        int n = g >> 1, ks = g & 1;
        vsrc[t] = &Vt[(long long)(h * HD + n * 16 + l16) * NTOK + jbase + (ks * 4 + q) * 8];
    }

    f32x4 zero4 = {0.f, 0.f, 0.f, 0.f};
    f32x4 pv[2][4];
#pragma unroll
    for (int m = 0; m < 2; m++)
#pragma unroll
        for (int n = 0; n < 4; n++) pv[m][n] = zero4;
    float sums[2][4] = {{0.f, 0.f, 0.f, 0.f}, {0.f, 0.f, 0.f, 0.f}};

    for (int jt = 0; jt < 8; ++jt) {
        const int j0 = jbase + jt * 64;
        __syncthreads();  // previous-iter consumers done with Kf/Vf/Et
#pragma unroll
        for (int t = 0; t < 4; t++) {
            int g = wid * 4 + t;
            gld_lds16(ksrc[t], &Kf[(g * 64 + lane) * 8]);
            gld_lds16(vsrc[t], &Vf[(g * 64 + lane) * 8]);
            ksrc[t] += 64 * CDIM;
            vsrc[t] += 64;
        }
        __syncthreads();  // drains DMA (vmcnt) + LDS visible
        // QK -> e -> Et (+ row sums)
#pragma unroll
        for (int tn = 0; tn < 2; tn++) {
            int tng = wn * 2 + tn;
            short8 bfr[4];
#pragma unroll
            for (int kt = 0; kt < 4; kt++)
                bfr[kt] = *(const short8*)&Kf[((tng * 4 + kt) * 64 + lane) * 8];
            int j = j0 + tng * 16 + l16;
            float cj = cls[j];
            float sc = 25.f * cj;
#pragma unroll
            for (int m = 0; m < 2; m++) {
                f32x4 acc = zero4;
#pragma unroll
                for (int kt = 0; kt < 4; kt++)
                    acc = __builtin_amdgcn_mfma_f32_16x16x32_bf16(af[m][kt], bfr[kt],
                                                                  acc, 0, 0, 0);
                int ibase = wm * 32 + m * 16 + q * 4;
#pragma unroll
                for (int r = 0; r < 4; r++) {
                    float mk = (cj > cls_i[m][r]) ? 1.f : 0.f;
                    float e = __expf(acc[r] * sc * mk);
                    sums[m][r] += e;
                    int il = ibase + r;
                    int jl = tng * 16 + l16;
                    Et[il * 64 + ((((jl >> 3) ^ (il & 7)) << 3) | (jl & 7))] = f2bf(e);
                }
            }
        }
        __syncthreads();
        {   // coalesced P store from Et
            int il = tid >> 2, c = tid & 3;
            int x = il & 7;
            short8 e0 = *(const short8*)&Et[il * 64 + (((2 * c) ^ x) << 3)];
            short8 e1 = *(const short8*)&Et[il * 64 + (((2 * c + 1) ^ x) << 3)];
            u16* dst = &P[((long long)(h * NTOK + i0 + il)) * NTOK + j0 + c * 16];
            *(short8*)&dst[0] = e0;
            *(short8*)&dst[8] = e1;
        }
        // PV: A from Et (swizzled), B from Vf; out tile i(64) x d(128)
#pragma unroll
        for (int ks = 0; ks < 2; ks++) {
            short8 a2[2];
#pragma unroll
            for (int m2 = 0; m2 < 2; m2++) {
                int il = wm * 32 + m2 * 16 + l16;
                int ch = ks * 4 + q;
                a2[m2] = *(const short8*)&Et[il * 64 + ((ch ^ (il & 7)) << 3)];
            }
#pragma unroll
            for (int n2 = 0; n2 < 4; n2++) {
                short8 b2 = *(const short8*)&Vf[(((wn * 4 + n2) * 2 + ks) * 64 + lane) * 8];
#pragma unroll
                for (int m2 = 0; m2 < 2; m2++)
                    pv[m2][n2] = __builtin_amdgcn_mfma_f32_16x16x32_bf16(
                        a2[m2], b2, pv[m2][n2], 0, 0, 0);
            }
        }
    }
    // row-sum partials (race-free: one writer per (wn,jc,h,row))
#pragma unroll
    for (int m = 0; m < 2; m++)
#pragma unroll
        for (int r = 0; r < 4; r++) {
            float s = sums[m][r];
            s += __shfl_xor(s, 1);
            s += __shfl_xor(s, 2);
            s += __shfl_xor(s, 4);
            s += __shfl_xor(s, 8);
            if (l16 == 0)
                Spart[((wn * 4 + jc) * NH + h) * NTOK + i0 + wm * 32 + m * 16 + q * 4 + r] = s;
        }
    // store PV partial to this jc's slab (bf16, plain stores, no atomics)
    u16* Xp = Xpart + (long long)jc * NTOK * CDIM;
#pragma unroll
    for (int m2 = 0; m2 < 2; m2++)
#pragma unroll
        for (int n2 = 0; n2 < 4; n2++)
#pragma unroll
            for (int r = 0; r < 4; r++) {
                int i = i0 + wm * 32 + m2 * 16 + q * 4 + r;
                int d = wn * 64 + n2 * 16 + l16;
                Xp[(long long)i * CDIM + h * HD + d] = f2bf(pv[m2][n2][r]);
            }
}

// ---------------------------------------------------------------- K4: merged epilogue: x=(sum Xpart)/S  and  output2
__global__ __launch_bounds__(256) void k_epi(const u16* __restrict__ Xpart,
                                             const float* __restrict__ Spart,
                                             const u16* __restrict__ P,
                                             const unsigned char* __restrict__ mask,
                                             float* __restrict__ out,
                                             float* __restrict__ out2) {
    __shared__ float red[256];
    __shared__ float sArr[NH];
    const int i = blockIdx.x;
    const int t = threadIdx.x;
    if (t < NH) {
        float s = 0.f;
#pragma unroll
        for (int g = 0; g < 8; g++) s += Spart[(g * NH + t) * NTOK + i];
        sArr[t] = s;
    }
    __syncthreads();
    // ---- part A: x row i (1024 cols, 4 per thread)
    {
        int c = t * 4;
        int h = c >> 7;
        float acc[4] = {0.f, 0.f, 0.f, 0.f};
#pragma unroll
        for (int jc = 0; jc < 4; jc++) {
            short4v v = *(const short4v*)&Xpart[(long long)jc * NTOK * CDIM +
                                                (long long)i * CDIM + c];
#pragma unroll
            for (int k = 0; k < 4; k++) acc[k] += bf2f((u16)v[k]);
        }
        float invs = 1.f / sArr[h];
        float4 o;
        o.x = acc[0] * invs; o.y = acc[1] * invs; o.z = acc[2] * invs; o.w = acc[3] * invs;
        *(float4*)&out[(long long)i * 2048 + c] = o;
    }
    // ---- part B: output2 row i (2048 cols, 8 per thread)
    float invS[NH];
#pragma unroll
    for (int h = 0; h < NH; h++) invS[h] = 1.f / (8.f * sArr[h]);
    const int c0 = t * 8;
    float a[8] = {0.f, 0.f, 0.f, 0.f, 0.f, 0.f, 0.f, 0.f};
#pragma unroll
    for (int h = 0; h < NH; h++) {
        short8 p = *(const short8*)&P[((long long)h * NTOK + i) * NTOK + c0];
#pragma unroll
        for (int k = 0; k < 8; k++) a[k] += bf2f((u16)p[k]) * invS[h];
    }
    const unsigned char* mrow = mask + (long long)i * NTOK + c0;
    float e[8];
    unsigned char mk[8];
    float part = 0.f;
#pragma unroll
    for (int k = 0; k < 8; k++) {
        e[k] = __expf(a[k]);
        mk[k] = mrow[k];
        if (mk[k]) part += e[k];
    }
    red[t] = part;
    __syncthreads();
    for (int s = 128; s > 0; s >>= 1) {
        if (t < s) red[t] += red[t + s];
        __syncthreads();
    }
    float invT = 1.f / red[0];
    float o[8];
#pragma unroll
    for (int k = 0; k < 8; k++) o[k] = mk[k] ? e[k] * invT : 0.f;
    float4 o0, o1;
    o0.x = o[0]; o0.y = o[1]; o0.z = o[2]; o0.w = o[3];
    o1.x = o[4]; o1.y = o[5]; o1.z = o[6]; o1.w = o[7];
    float* dst = out2 + (long long)i * NTOK + c0;
    *(float4*)dst = o0;
    *(float4*)(dst + 4) = o1;
}

// ---------------------------------------------------------------- launcher
extern "C" void kernel_launch(void* const* d_in, const int* in_sizes, int n_in,
                              void* d_out, int out_size, void* d_ws,
                              size_t ws_size, hipStream_t stream) {
    (void)in_sizes; (void)n_in; (void)out_size; (void)ws_size;
    const float* x = (const float*)d_in[0];
    const float* cls = (const float*)d_in[1];
    // d_in[2] = fg_score: unused by the reference
    const float* Wq = (const float*)d_in[3];
    float* out = (float*)d_out;
    char* ws = (char*)d_ws;

    // Region [0, 23068672): early buffers (Xb/Wb dead after k_qkvn) overlaid
    // with Xpart/Spart (written only by k_attn7 afterwards).
    u16* Xb = (u16*)(ws + 0);                      //  4 MB  [2048,1024]
    u16* Wb = (u16*)(ws + 4194304);                //  6 MB  [3072,1024]
    u16* Xpart = (u16*)(ws + 0);                   // 16 MB  [4][2048,1024] bf16 PV partials
    float* Spart = (float*)(ws + 16777216);        // 512 KB [8][8,2048] row-sum partials
    u16* Qn = (u16*)(ws + 23068672);               //  4 MB
    u16* Kn = (u16*)(ws + 27262976);               //  4 MB
    u16* Vn = (u16*)(ws + 31457280);               //  4 MB
    u16* Vt = (u16*)(ws + 35651584);               //  4 MB  [1024,2048]
    unsigned char* mask = (unsigned char*)(ws + 39845888);  // 4 MB [2048,2048]
    u16* P = (u16*)(ws + 44040192);                // 67 MB [8,2048,2048]

    // 1. cast x and W to bf16
    k_cast<<<1024, 256, 0, stream>>>(x, Wq, Xb, Wb);

    // 2. fused QKV GEMM + norm + x_ori + Vt (replaces gemm, k_norm, k_vt)
    k_qkvn<<<dim3(24, 16), 256, 0, stream>>>(Xb, Wb, Qn, Kn, Vn, Vt, out);

    // 3. sim mask = (Vn @ Vn^T / 8 > 0.75) -> u8, symmetric (lower blocks only)
    k_gemm_mask<<<dim3(16, 16), 256, 0, stream>>>(
        Vn, Vn, mask, CDIM, CDIM, CDIM, NTOK, 0.125f);

    // 4. fused logits+exp -> P, partial row sums, partial PV -> Xpart
    k_attn7<<<dim3(32, 4, NH), 256, 0, stream>>>(Qn, Kn, Vt, cls, P, Spart, Xpart);

    // 5. merged epilogue: x and output2
    k_epi<<<NTOK, 256, 0, stream>>>(Xpart, Spart, P, mask, out,
                                    out + (long long)NTOK * 2048);
}